// Round 6
// baseline (2750.035 us; speedup 1.0000x reference)
//
#include <hip/hip_runtime.h>
#include <cmath>

namespace {

constexpr int kWin = 100;
constexpr int kNin = 700;

// f32 transposed-weight offsets (floats) inside d_ws.
constexpr size_t OFF1 = 0;        // WT1 [700][512]
constexpr size_t OFF2 = 358400;   // WT2 [512][256]
constexpr size_t OFF3 = 489472;   // WT3 [256][128]
constexpr size_t OFF4 = 522240;   // WT4 [128][256]
constexpr size_t OFF5 = 555008;   // WT5 [256][512]
constexpr size_t OFF6 = 686080;   // WT6 [512][700]
constexpr size_t OFF_END = 1044480;          // floats used by weights (4.18 MB, L2-resident)
constexpr size_t XM_OFF_U64 = OFF_END / 2;   // u64 index into ws for xmasks
// xmask layout: [B=512][T=100][12] u64 words (11 used + 1 pad, always written)

__global__ void transpose_k(const float* __restrict__ src, float* __restrict__ dst,
                            int H, int K) {
  int idx = blockIdx.x * blockDim.x + threadIdx.x;
  if (idx < H * K) {
    int h = idx / K;
    int k = idx - h * K;
    dst[(size_t)k * H + h] = src[idx];  // dst[K][H] = src[H][K]^T
  }
}

// Build input spike bitmasks: one block per (row, t), 256 threads.
// Word w covers input neurons h in [w*64, w*64+64), bit = h%64.
__global__ __launch_bounds__(256) void xmask_k(const float* __restrict__ x,
                                               unsigned long long* __restrict__ xm) {
  const int bid = blockIdx.x;  // row * 100 + t
  const int tid = threadIdx.x;
  const int lane = tid & 63;
  const int wv = tid >> 6;  // 0..3
  const float* xr = x + (size_t)bid * kNin;
  unsigned long long* dst = xm + (size_t)bid * 12;
#pragma unroll
  for (int s = 0; s < 3; ++s) {
    const int h = s * 256 + tid;
    const bool p = (h < kNin) ? (xr[h] != 0.0f) : false;
    const unsigned long long b = __ballot(p);
    if (lane == 0) dst[s * 4 + wv] = b;  // s=2,wv=3 writes pad word 11 (= 0)
  }
}

// One LIF layer (R2 structure, verified passing). 1024 threads per batch row:
// kp = tid>>8 splits the active-column sum 4 ways (32-bit mask chunks,
// c % 4 == kp); ht = tid&255 covers the output neurons (h = s*256 + ht).
// Partials combined via LDS in the fixed order ((p0+p1)+p2)+p3.
// R6 deltas vs R2 (both semantics-preserving):
//   (a) mask chunks batch-preloaded into registers (one wait) instead of one
//       serialized LDS/global round-trip per chunk;
//   (b) two interleaved f64 accumulators (a0 += f0,f2; a1 += f1,f3) to halve
//       the dependent-add chain; final a0+a1 at the parts write.
// mem_new = mem*alpha + sum(active WT columns); spike = mem_new > 0.3;
// mem = (mem_new < 0.3) ? mem_new : 0.  ((1-o_spike) factor is redundant:
// the hard reset already zeroed spiking neurons; VRESET = 0.)
template <int K, int H, bool BUILD, typename FCh>
__device__ __forceinline__ void lif(const float* __restrict__ WT, FCh&& chunk,
                                    double* mem, unsigned long long* mOut,
                                    double (*part)[3][256],  // [kp][s][ht]
                                    float* outRow,
                                    int kp, int ht, int lane, int wv4,
                                    double alpha) {
  constexpr int NS = (H + 255) / 256;
  constexpr int NC = (K + 31) / 32;   // 32-bit mask chunks
  constexpr int MAXC = (NC + 3) / 4;  // chunks per kp group

  double a0[NS], a1[NS];
#pragma unroll
  for (int s = 0; s < NS; ++s) { a0[s] = 0.0; a1[s] = 0.0; }

  // (a) Batched preload of this kp's mask chunks: all loads issue
  // back-to-back, one wait, instead of a latency round-trip per chunk.
  unsigned mv[MAXC];
#pragma unroll
  for (int j = 0; j < MAXC; ++j) {
    const int c = kp + 4 * j;
    mv[j] = (c < NC) ? chunk(c) : 0u;
  }

#pragma unroll
  for (int j = 0; j < MAXC; ++j) {
    unsigned m = __builtin_amdgcn_readfirstlane(mv[j]);
    const int c = kp + 4 * j;
    const float* __restrict__ cbase = WT + (size_t)c * 32 * H;
    const int cnt = __builtin_popcount(m);
    int i = 0;
    for (; i + 4 <= cnt; i += 4) {
      const int b0 = __builtin_ctz(m); m &= m - 1;
      const int b1 = __builtin_ctz(m); m &= m - 1;
      const int b2 = __builtin_ctz(m); m &= m - 1;
      const int b3 = __builtin_ctz(m); m &= m - 1;
      const float* p0 = cbase + b0 * H;
      const float* p1 = cbase + b1 * H;
      const float* p2 = cbase + b2 * H;
      const float* p3 = cbase + b3 * H;
#pragma unroll
      for (int s = 0; s < NS; ++s) {
        const int h = s * 256 + ht;
        if ((s + 1) * 256 <= H || h < H) {
          const float f0 = p0[h];
          const float f1 = p1[h];
          const float f2 = p2[h];
          const float f3 = p3[h];
          a0[s] += (double)f0;  // (b) two independent 2-deep chains
          a1[s] += (double)f1;
          a0[s] += (double)f2;
          a1[s] += (double)f3;
        }
      }
    }
    for (; i + 2 <= cnt; i += 2) {
      const int b0 = __builtin_ctz(m); m &= m - 1;
      const int b1 = __builtin_ctz(m); m &= m - 1;
      const float* p0 = cbase + b0 * H;
      const float* p1 = cbase + b1 * H;
#pragma unroll
      for (int s = 0; s < NS; ++s) {
        const int h = s * 256 + ht;
        if ((s + 1) * 256 <= H || h < H) {
          const float f0 = p0[h];
          const float f1 = p1[h];
          a0[s] += (double)f0;
          a1[s] += (double)f1;
        }
      }
    }
    if (i < cnt) {
      const int b0 = __builtin_ctz(m);
      const float* p0 = cbase + b0 * H;
#pragma unroll
      for (int s = 0; s < NS; ++s) {
        const int h = s * 256 + ht;
        if ((s + 1) * 256 <= H || h < H) a0[s] += (double)p0[h];
      }
    }
  }

#pragma unroll
  for (int s = 0; s < NS; ++s) part[kp][s][ht] = a0[s] + a1[s];
  __syncthreads();  // SYNC1: partials ready

  bool pred[NS];
#pragma unroll
  for (int s = 0; s < NS; ++s) {
    const int h = s * 256 + ht;
    if ((s + 1) * 256 <= H || h < H) {
      const double p01 = part[0][s][ht] + part[1][s][ht];
      const double tot = (p01 + part[2][s][ht]) + part[3][s][ht];
      const double mm = mem[s] * alpha + tot;
      pred[s] = (mm > 0.3);
      mem[s] = (mm < 0.3) ? mm : 0.0;
      if (!BUILD) {
        if (kp == s) outRow[h] = pred[s] ? 1.0f : 0.0f;  // slot s stored by kp==s
      }
    } else {
      pred[s] = false;
    }
  }
  if (BUILD) {
#pragma unroll
    for (int s = 0; s < NS; ++s) {
      const unsigned long long b = __ballot(pred[s]);
      if (kp == 0 && lane == 0) mOut[s * 4 + wv4] = b;
    }
    __syncthreads();  // SYNC2: next layer's mask ready
  }
}

// 512 blocks x 1024 threads, one batch row per block. Steps 0..4 of the
// reference (zero-padded input) provably keep all state at 0, so only the
// 100 live steps run.
__global__ __launch_bounds__(1024, 8) void snn_main(
    const float* __restrict__ wsf, const unsigned long long* __restrict__ xmask,
    float* __restrict__ out) {
  const int tid = threadIdx.x;
  const int kp = tid >> 8;         // 0..3
  const int ht = tid & 255;
  const int lane = tid & 63;
  const int wv4 = (tid >> 6) & 3;  // wave index within kp group
  const int row = blockIdx.x;

  const float* WT1 = wsf + OFF1;
  const float* WT2 = wsf + OFF2;
  const float* WT3 = wsf + OFF3;
  const float* WT4 = wsf + OFF4;
  const float* WT5 = wsf + OFF5;
  const float* WT6 = wsf + OFF6;

  __shared__ unsigned long long mk[2][12];
  __shared__ double parts[2][4][3][256];  // [pingpong][kp][s][ht]

  // Per-thread membrane state (f64); slot s covers neuron h = s*256 + ht.
  double m1[2] = {0.0, 0.0};
  double m2[1] = {0.0};
  double m3[1] = {0.0};
  double m4[1] = {0.0};
  double m5[2] = {0.0, 0.0};
  double m6[3] = {0.0, 0.0, 0.0};

  const double alpha = exp(-1.0 / 3.0);

  const unsigned long long* xmRow = xmask + (size_t)row * kWin * 12;
  float* outRowBase = out + (size_t)row * kWin * kNin;

  for (int t = 0; t < kWin; ++t) {
    const unsigned* xm32 = (const unsigned*)(xmRow + (size_t)t * 12);
    const unsigned* mk0 = (const unsigned*)&mk[0][0];
    const unsigned* mk1 = (const unsigned*)&mk[1][0];

    lif<700, 512, true>(WT1, [&](int c) { return xm32[c]; }, m1, mk[0],
                        parts[0], nullptr, kp, ht, lane, wv4, alpha);
    lif<512, 256, true>(WT2, [&](int c) { return mk0[c]; }, m2, mk[1],
                        parts[1], nullptr, kp, ht, lane, wv4, alpha);
    lif<256, 128, true>(WT3, [&](int c) { return mk1[c]; }, m3, mk[0],
                        parts[0], nullptr, kp, ht, lane, wv4, alpha);
    lif<128, 256, true>(WT4, [&](int c) { return mk0[c]; }, m4, mk[1],
                        parts[1], nullptr, kp, ht, lane, wv4, alpha);
    lif<256, 512, true>(WT5, [&](int c) { return mk1[c]; }, m5, mk[0],
                        parts[0], nullptr, kp, ht, lane, wv4, alpha);
    float* outRow = outRowBase + (size_t)t * kNin;
    lif<512, 700, false>(WT6, [&](int c) { return mk0[c]; }, m6, nullptr,
                         parts[1], outRow, kp, ht, lane, wv4, alpha);
  }
}

}  // namespace

extern "C" void kernel_launch(void* const* d_in, const int* in_sizes, int n_in,
                              void* d_out, int out_size, void* d_ws, size_t ws_size,
                              hipStream_t stream) {
  const float* x = (const float*)d_in[0];
  float* ws = (float*)d_ws;
  unsigned long long* xm = (unsigned long long*)d_ws + XM_OFF_U64;
  float* out = (float*)d_out;

  // Transpose all weights into workspace (f32): dst[K][H] = W[H][K]^T.
  struct TK { int H, K; size_t off; int idx; };
  const TK tk[6] = {
      {512, 700, OFF1, 1},  // W_ih1
      {256, 512, OFF2, 2},  // W_h1h2
      {128, 256, OFF3, 3},  // W_h2h3
      {256, 128, OFF4, 4},  // W_h3h2
      {512, 256, OFF5, 5},  // W_h2h1
      {700, 512, OFF6, 6},  // W_h1o
  };
  for (int i = 0; i < 6; ++i) {
    const int n = tk[i].H * tk[i].K;
    transpose_k<<<(n + 255) / 256, 256, 0, stream>>>(
        (const float*)d_in[tk[i].idx], ws + tk[i].off, tk[i].H, tk[i].K);
  }

  // Precompute input spike bitmasks for all (row, t).
  xmask_k<<<512 * kWin, 256, 0, stream>>>(x, xm);

  snn_main<<<512, 1024, 0, stream>>>(ws, xm, out);
}

// Round 7
// 1141.111 us; speedup vs baseline: 2.4100x; 2.4100x over previous
//
#include <hip/hip_runtime.h>
#include <cmath>

namespace {

constexpr int kWin = 100;
constexpr int kNin = 700;

// f32 transposed-weight offsets (floats) inside d_ws.
constexpr size_t OFF1 = 0;        // WT1 [700][512]
constexpr size_t OFF2 = 358400;   // WT2 [512][256]
constexpr size_t OFF3 = 489472;   // WT3 [256][128]
constexpr size_t OFF4 = 522240;   // WT4 [128][256]
constexpr size_t OFF5 = 555008;   // WT5 [256][512]
constexpr size_t OFF6 = 686080;   // WT6 [512][700]
constexpr size_t OFF_END = 1044480;          // floats used by weights (4.18 MB, L2-resident)
constexpr size_t XM_OFF_U64 = OFF_END / 2;   // u64 index into ws for xmasks
// xmask layout: [B=512][T=100][12] u64 words (11 used + 1 pad, always written)

__global__ void transpose_k(const float* __restrict__ src, float* __restrict__ dst,
                            int H, int K) {
  int idx = blockIdx.x * blockDim.x + threadIdx.x;
  if (idx < H * K) {
    int h = idx / K;
    int k = idx - h * K;
    dst[(size_t)k * H + h] = src[idx];  // dst[K][H] = src[H][K]^T
  }
}

// Build input spike bitmasks: one block per (row, t), 256 threads.
// Word w covers input neurons h in [w*64, w*64+64), bit = h%64.
__global__ __launch_bounds__(256) void xmask_k(const float* __restrict__ x,
                                               unsigned long long* __restrict__ xm) {
  const int bid = blockIdx.x;  // row * 100 + t
  const int tid = threadIdx.x;
  const int lane = tid & 63;
  const int wv = tid >> 6;  // 0..3
  const float* xr = x + (size_t)bid * kNin;
  unsigned long long* dst = xm + (size_t)bid * 12;
#pragma unroll
  for (int s = 0; s < 3; ++s) {
    const int h = s * 256 + tid;
    const bool p = (h < kNin) ? (xr[h] != 0.0f) : false;
    const unsigned long long b = __ballot(p);
    if (lane == 0) dst[s * 4 + wv] = b;  // s=2,wv=3 writes pad word 11 (= 0)
  }
}

// One LIF layer (R2 structure, verified passing). 1024 threads per batch row:
// kp = tid>>8 splits the active-column sum 4 ways (32-bit mask chunks,
// c % 4 == kp); ht = tid&255 covers the output neurons (h = s*256 + ht).
// Partials combined via LDS in the fixed order ((p0+p1)+p2)+p3.
// R7 deltas vs R2 (scalar-register-only, codegen-neutral):
//   (a) rolling chunk prefetch: chunk c+4's load issues at the top of
//       iteration c and is consumed next iteration -> its latency hides
//       under the current chunk's column walk. One extra VGPR, no arrays.
//   (b) tree-reassociated adds in the 4-col body (transient temps, chain
//       depth 4 -> 2). f64 ordering noise is far below the spike margin
//       (absmax stayed exactly 0.0 across three full-reorder rounds).
// mem_new = mem*alpha + sum(active WT columns); spike = mem_new > 0.3;
// mem = (mem_new < 0.3) ? mem_new : 0.  ((1-o_spike) factor is redundant:
// the hard reset already zeroed spiking neurons; VRESET = 0.)
template <int K, int H, bool BUILD, typename FCh>
__device__ __forceinline__ void lif(const float* __restrict__ WT, FCh&& chunk,
                                    double* mem, unsigned long long* mOut,
                                    double (*part)[3][256],  // [kp][s][ht]
                                    float* outRow,
                                    int kp, int ht, int lane, int wv4,
                                    double alpha) {
  constexpr int NS = (H + 255) / 256;
  constexpr int NC = (K + 31) / 32;  // 32-bit mask chunks
  double acc[NS];
#pragma unroll
  for (int s = 0; s < NS; ++s) acc[s] = 0.0;

  unsigned mNext = chunk(kp);  // (a) first chunk issued ahead of the loop
  for (int c = kp; c < NC; c += 4) {
    unsigned m = __builtin_amdgcn_readfirstlane(mNext);
    if (c + 4 < NC) mNext = chunk(c + 4);  // (a) overlap next chunk's latency
    const float* __restrict__ cbase = WT + (size_t)c * 32 * H;
    const int cnt = __builtin_popcount(m);
    int i = 0;
    for (; i + 4 <= cnt; i += 4) {
      const int b0 = __builtin_ctz(m); m &= m - 1;
      const int b1 = __builtin_ctz(m); m &= m - 1;
      const int b2 = __builtin_ctz(m); m &= m - 1;
      const int b3 = __builtin_ctz(m); m &= m - 1;
      const float* p0 = cbase + b0 * H;
      const float* p1 = cbase + b1 * H;
      const float* p2 = cbase + b2 * H;
      const float* p3 = cbase + b3 * H;
#pragma unroll
      for (int s = 0; s < NS; ++s) {
        const int h = s * 256 + ht;
        if ((s + 1) * 256 <= H || h < H) {
          const float f0 = p0[h];
          const float f1 = p1[h];
          const float f2 = p2[h];
          const float f3 = p3[h];
          const double t01 = (double)f0 + (double)f1;  // (b) tree reassociation
          const double t23 = (double)f2 + (double)f3;
          acc[s] += t01 + t23;
        }
      }
    }
    for (; i < cnt; ++i) {
      const int b0 = __builtin_ctz(m); m &= m - 1;
      const float* p0 = cbase + b0 * H;
#pragma unroll
      for (int s = 0; s < NS; ++s) {
        const int h = s * 256 + ht;
        if ((s + 1) * 256 <= H || h < H) acc[s] += (double)p0[h];
      }
    }
  }

#pragma unroll
  for (int s = 0; s < NS; ++s) part[kp][s][ht] = acc[s];
  __syncthreads();  // SYNC1: partials ready

  bool pred[NS];
#pragma unroll
  for (int s = 0; s < NS; ++s) {
    const int h = s * 256 + ht;
    if ((s + 1) * 256 <= H || h < H) {
      const double p01 = part[0][s][ht] + part[1][s][ht];
      const double tot = (p01 + part[2][s][ht]) + part[3][s][ht];
      const double mm = mem[s] * alpha + tot;
      pred[s] = (mm > 0.3);
      mem[s] = (mm < 0.3) ? mm : 0.0;
      if (!BUILD) {
        if (kp == s) outRow[h] = pred[s] ? 1.0f : 0.0f;  // slot s stored by kp==s
      }
    } else {
      pred[s] = false;
    }
  }
  if (BUILD) {
#pragma unroll
    for (int s = 0; s < NS; ++s) {
      const unsigned long long b = __ballot(pred[s]);
      if (kp == 0 && lane == 0) mOut[s * 4 + wv4] = b;
    }
    __syncthreads();  // SYNC2: next layer's mask ready
  }
}

// 512 blocks x 1024 threads, one batch row per block. Steps 0..4 of the
// reference (zero-padded input) provably keep all state at 0, so only the
// 100 live steps run.
__global__ __launch_bounds__(1024, 8) void snn_main(
    const float* __restrict__ wsf, const unsigned long long* __restrict__ xmask,
    float* __restrict__ out) {
  const int tid = threadIdx.x;
  const int kp = tid >> 8;         // 0..3
  const int ht = tid & 255;
  const int lane = tid & 63;
  const int wv4 = (tid >> 6) & 3;  // wave index within kp group
  const int row = blockIdx.x;

  const float* WT1 = wsf + OFF1;
  const float* WT2 = wsf + OFF2;
  const float* WT3 = wsf + OFF3;
  const float* WT4 = wsf + OFF4;
  const float* WT5 = wsf + OFF5;
  const float* WT6 = wsf + OFF6;

  __shared__ unsigned long long mk[2][12];
  __shared__ double parts[2][4][3][256];  // [pingpong][kp][s][ht]

  // Per-thread membrane state (f64); slot s covers neuron h = s*256 + ht.
  double m1[2] = {0.0, 0.0};
  double m2[1] = {0.0};
  double m3[1] = {0.0};
  double m4[1] = {0.0};
  double m5[2] = {0.0, 0.0};
  double m6[3] = {0.0, 0.0, 0.0};

  const double alpha = exp(-1.0 / 3.0);

  const unsigned long long* xmRow = xmask + (size_t)row * kWin * 12;
  float* outRowBase = out + (size_t)row * kWin * kNin;

  for (int t = 0; t < kWin; ++t) {
    const unsigned* xm32 = (const unsigned*)(xmRow + (size_t)t * 12);
    const unsigned* mk0 = (const unsigned*)&mk[0][0];
    const unsigned* mk1 = (const unsigned*)&mk[1][0];

    lif<700, 512, true>(WT1, [&](int c) { return xm32[c]; }, m1, mk[0],
                        parts[0], nullptr, kp, ht, lane, wv4, alpha);
    lif<512, 256, true>(WT2, [&](int c) { return mk0[c]; }, m2, mk[1],
                        parts[1], nullptr, kp, ht, lane, wv4, alpha);
    lif<256, 128, true>(WT3, [&](int c) { return mk1[c]; }, m3, mk[0],
                        parts[0], nullptr, kp, ht, lane, wv4, alpha);
    lif<128, 256, true>(WT4, [&](int c) { return mk0[c]; }, m4, mk[1],
                        parts[1], nullptr, kp, ht, lane, wv4, alpha);
    lif<256, 512, true>(WT5, [&](int c) { return mk1[c]; }, m5, mk[0],
                        parts[0], nullptr, kp, ht, lane, wv4, alpha);
    float* outRow = outRowBase + (size_t)t * kNin;
    lif<512, 700, false>(WT6, [&](int c) { return mk0[c]; }, m6, nullptr,
                         parts[1], outRow, kp, ht, lane, wv4, alpha);
  }
}

}  // namespace

extern "C" void kernel_launch(void* const* d_in, const int* in_sizes, int n_in,
                              void* d_out, int out_size, void* d_ws, size_t ws_size,
                              hipStream_t stream) {
  const float* x = (const float*)d_in[0];
  float* ws = (float*)d_ws;
  unsigned long long* xm = (unsigned long long*)d_ws + XM_OFF_U64;
  float* out = (float*)d_out;

  // Transpose all weights into workspace (f32): dst[K][H] = W[H][K]^T.
  struct TK { int H, K; size_t off; int idx; };
  const TK tk[6] = {
      {512, 700, OFF1, 1},  // W_ih1
      {256, 512, OFF2, 2},  // W_h1h2
      {128, 256, OFF3, 3},  // W_h2h3
      {256, 128, OFF4, 4},  // W_h3h2
      {512, 256, OFF5, 5},  // W_h2h1
      {700, 512, OFF6, 6},  // W_h1o
  };
  for (int i = 0; i < 6; ++i) {
    const int n = tk[i].H * tk[i].K;
    transpose_k<<<(n + 255) / 256, 256, 0, stream>>>(
        (const float*)d_in[tk[i].idx], ws + tk[i].off, tk[i].H, tk[i].K);
  }

  // Precompute input spike bitmasks for all (row, t).
  xmask_k<<<512 * kWin, 256, 0, stream>>>(x, xm);

  snn_main<<<512, 1024, 0, stream>>>(ws, xm, out);
}